// Round 7
// baseline (6541.972 us; speedup 1.0000x reference)
//
#include <hip/hip_runtime.h>

// C = triu(A @ B), A,B upper-triangular fp32 4096x4096.
// R7: R5's balanced split-K grid (CH=8, 1000 wgs, atomics for multi-chunk
// tiles) + DEPTH-2 register prefetch: loads for phase p+2 issued at phase p,
// so phase p's ds_write waits on ~2-phase-old loads (vmcnt stall removed).
// K=64 phases, 2-deep LDS dbuf (RS=72 padded), 1 barrier/phase.

#define N   4096
#define NB  32      // N / BM
#define BM  128
#define PK  64      // K per pipeline phase
#define CH  8       // K-blocks (128 wide) per chunk
#define NWG 1000    // sum over d of (NB-d)*ceil((d+1)/CH)  [NB=32, CH=8]
#define RS  72      // LDS row stride in ushorts (64 + 8 pad)

typedef __attribute__((ext_vector_type(8))) __bf16 bf16x8;
typedef __attribute__((ext_vector_type(4))) float  floatx4;
typedef __attribute__((ext_vector_type(8))) unsigned short ushort8;

__device__ __forceinline__ unsigned short f32_to_bf16_rne(float f) {
    unsigned u = __builtin_bit_cast(unsigned, f);
    unsigned r = u + 0x7fffu + ((u >> 16) & 1u);
    return (unsigned short)(r >> 16);
}

// --- fused prep: A->bf16 (upper blocks), B->bf16 transposed (needed blocks),
//     zero C where trimm won't plain-store (strictly-lower + atomic tiles) ---
__global__ __launch_bounds__(256)
void prep_kernel(const float* __restrict__ A, const float* __restrict__ B,
                 unsigned short* __restrict__ Ab, unsigned short* __restrict__ Bt,
                 float* __restrict__ C) {
    __shared__ float tile[64][65];
    const int bx = blockIdx.x, by = blockIdx.y;      // 64-granule col/row
    const int x0 = bx * 64, y0 = by * 64;
    const int xb = bx >> 1, yb = by >> 1;            // 128-blocks
    const int t  = threadIdx.x;
    const int tr = t >> 2, tc = (t & 3) * 16;        // 64x(16/thread)

    if (xb >= yb) {   // A: needed iff k-block >= row-block
        const float* src = A + (size_t)(y0 + tr) * N + x0 + tc;
        const float4 v0 = ((const float4*)src)[0];
        const float4 v1 = ((const float4*)src)[1];
        const float4 v2 = ((const float4*)src)[2];
        const float4 v3 = ((const float4*)src)[3];
        ushort8 o0, o1;
        o0[0]=f32_to_bf16_rne(v0.x); o0[1]=f32_to_bf16_rne(v0.y);
        o0[2]=f32_to_bf16_rne(v0.z); o0[3]=f32_to_bf16_rne(v0.w);
        o0[4]=f32_to_bf16_rne(v1.x); o0[5]=f32_to_bf16_rne(v1.y);
        o0[6]=f32_to_bf16_rne(v1.z); o0[7]=f32_to_bf16_rne(v1.w);
        o1[0]=f32_to_bf16_rne(v2.x); o1[1]=f32_to_bf16_rne(v2.y);
        o1[2]=f32_to_bf16_rne(v2.z); o1[3]=f32_to_bf16_rne(v2.w);
        o1[4]=f32_to_bf16_rne(v3.x); o1[5]=f32_to_bf16_rne(v3.y);
        o1[6]=f32_to_bf16_rne(v3.z); o1[7]=f32_to_bf16_rne(v3.w);
        unsigned short* dst = Ab + (size_t)(y0 + tr) * N + x0 + tc;
        ((ushort8*)dst)[0] = o0;
        ((ushort8*)dst)[1] = o1;
    }
    if (xb <= yb) {   // Bt[j][k]=B[k][j]: needed iff k-block <= j-block
        const float* src = B + (size_t)(x0 + tr) * N + y0 + tc;   // B[k][j]
        const float4 v0 = ((const float4*)src)[0];
        const float4 v1 = ((const float4*)src)[1];
        const float4 v2 = ((const float4*)src)[2];
        const float4 v3 = ((const float4*)src)[3];
        float* d = &tile[tr][tc];
        d[0]=v0.x; d[1]=v0.y; d[2]=v0.z; d[3]=v0.w;
        d[4]=v1.x; d[5]=v1.y; d[6]=v1.z; d[7]=v1.w;
        d[8]=v2.x; d[9]=v2.y; d[10]=v2.z; d[11]=v2.w;
        d[12]=v3.x; d[13]=v3.y; d[14]=v3.z; d[15]=v3.w;
        __syncthreads();
        ushort8 o0, o1;
        #pragma unroll
        for (int i = 0; i < 8; ++i) o0[i] = f32_to_bf16_rne(tile[tc + i][tr]);
        #pragma unroll
        for (int i = 0; i < 8; ++i) o1[i] = f32_to_bf16_rne(tile[tc + 8 + i][tr]);
        unsigned short* dst = Bt + (size_t)(y0 + tr) * N + x0 + tc;
        ((ushort8*)dst)[0] = o0;
        ((ushort8*)dst)[1] = o1;
    }
    // C zeros: strictly-lower 128-blocks, and atomic tiles (d>=CH)
    if (xb < yb || (xb - yb) >= CH) {
        float4 z = {0.f, 0.f, 0.f, 0.f};
        float* dst = C + (size_t)(y0 + tr) * N + x0 + tc;
        ((float4*)dst)[0] = z; ((float4*)dst)[1] = z;
        ((float4*)dst)[2] = z; ((float4*)dst)[3] = z;
    }
}

// --- split-K triangular MFMA GEMM, K=64 phases, DEPTH-2 reg prefetch ---
__global__ __launch_bounds__(256, 2)
void trimm_kernel(const unsigned short* __restrict__ Ab,
                  const unsigned short* __restrict__ Bt,
                  float* __restrict__ C) {
    __shared__ unsigned short sA[2][BM * RS];   // padded rows (144 B stride)
    __shared__ unsigned short sB[2][BM * RS];

    // ---- decode blockIdx -> (tile bi,bj ; K-chunk); expensive diagonals first
    int rem = blockIdx.x;
    int d = 0, per = 1;
    for (int dd = NB - 1; dd >= 0; --dd) {
        const int p   = (dd + CH) / CH;          // ceil((dd+1)/CH)
        const int cnt = (NB - dd) * p;
        if (rem < cnt) { d = dd; per = p; break; }
        rem -= cnt;
    }
    const int tile  = rem / per;
    const int chunk = rem - tile * per;
    const int bi = tile, bj = tile + d;
    const int c    = d + 1;
    const int base = c / per, extra = c - base * per;
    const int kb0  = bi + chunk * base + (chunk < extra ? chunk : extra);
    const int len  = base + (chunk < extra ? 1 : 0);

    const int tid  = threadIdx.x;
    const int w    = tid >> 6;
    const int lane = tid & 63;
    const int quad = lane >> 4;
    const int l15  = lane & 15;

    const int m0 = (w >> 1) * 64;
    const int n0 = (w & 1) * 64;
    const int row0 = bi * BM;
    const int col0 = bj * BM;

    floatx4 acc[4][4] = {};

    // staging map: wave w stages rows [32w,32w+32); instr i -> row 32w+8i+(lane>>3)
    const int srow8 = lane >> 3;
    const int sk    = (lane & 7) * 8;
    int lofs[4];
    const unsigned short* gA[4];
    const unsigned short* gB[4];
    #pragma unroll
    for (int i = 0; i < 4; ++i) {
        const int r = w * 32 + i * 8 + srow8;
        lofs[i] = r * RS + sk;
        gA[i] = Ab + (size_t)(row0 + r) * N + kb0 * BM + sk;
        gB[i] = Bt + (size_t)(col0 + r) * N + kb0 * BM + sk;
    }

    const int np = len * 2;            // K=64 phases (np >= 2)

    // depth-2 register pipeline: slot (ph & 1) holds phase ph's data
    ushort8 aR[2][4], bR[2][4];
    #pragma unroll
    for (int i = 0; i < 4; ++i) { aR[0][i] = *(const ushort8*)gA[i]; gA[i] += PK; }
    #pragma unroll
    for (int i = 0; i < 4; ++i) { bR[0][i] = *(const ushort8*)gB[i]; gB[i] += PK; }
    #pragma unroll
    for (int i = 0; i < 4; ++i) { aR[1][i] = *(const ushort8*)gA[i]; gA[i] += PK; }
    #pragma unroll
    for (int i = 0; i < 4; ++i) { bR[1][i] = *(const ushort8*)gB[i]; gB[i] += PK; }

    for (int ph = 0; ph < np; ++ph) {
        const int buf = ph & 1;
        // R -> LDS (vmcnt waits on loads issued 2 phases ago)
        #pragma unroll
        for (int i = 0; i < 4; ++i) *(ushort8*)&sA[buf][lofs[i]] = aR[buf][i];
        #pragma unroll
        for (int i = 0; i < 4; ++i) *(ushort8*)&sB[buf][lofs[i]] = bR[buf][i];
        __syncthreads();
        // issue loads for phase ph+2 into the slot just flushed
        if (ph + 2 < np) {
            #pragma unroll
            for (int i = 0; i < 4; ++i) { aR[buf][i] = *(const ushort8*)gA[i]; gA[i] += PK; }
            #pragma unroll
            for (int i = 0; i < 4; ++i) { bR[buf][i] = *(const ushort8*)gB[i]; gB[i] += PK; }
        }
        // compute phase ph from LDS
        #pragma unroll
        for (int h = 0; h < 2; ++h) {
            bf16x8 af[4], bfr[4];
            #pragma unroll
            for (int t = 0; t < 4; ++t) {
                af[t]  = *(const bf16x8*)&sA[buf][(m0 + t * 16 + l15) * RS + h * 32 + quad * 8];
                bfr[t] = *(const bf16x8*)&sB[buf][(n0 + t * 16 + l15) * RS + h * 32 + quad * 8];
            }
            #pragma unroll
            for (int tm = 0; tm < 4; ++tm)
                #pragma unroll
                for (int tn = 0; tn < 4; ++tn)
                    acc[tm][tn] = __builtin_amdgcn_mfma_f32_16x16x32_bf16(
                        af[tm], bfr[tn], acc[tm][tn], 0, 0, 0);
        }
        // no trailing barrier: phase ph+1 writes the other LDS buffer; this
        // buffer is next written at ph+2, after barrier ph+1 -> WAR safe
    }

    // ---- epilogue. C/D layout: col=lane&15, row=quad*4+r.
    #pragma unroll
    for (int tm = 0; tm < 4; ++tm) {
        const int grow_base = row0 + m0 + tm * 16 + quad * 4;
        #pragma unroll
        for (int tn = 0; tn < 4; ++tn) {
            const int gcol = col0 + n0 + tn * 16 + l15;
            #pragma unroll
            for (int r = 0; r < 4; ++r) {
                const int grow = grow_base + r;
                float* p = C + (size_t)grow * N + gcol;
                const float v = acc[tm][tn][r];
                if (per > 1) {
                    atomicAdd(p, v);           // tile pre-zeroed by prep
                } else if (d != 0) {
                    *p = v;                    // sole writer, full block
                } else {
                    *p = (gcol >= grow) ? v : 0.0f;   // diagonal block
                }
            }
        }
    }
}

extern "C" void kernel_launch(void* const* d_in, const int* in_sizes, int n_in,
                              void* d_out, int out_size, void* d_ws, size_t ws_size,
                              hipStream_t stream) {
    const float* A = (const float*)d_in[0];
    const float* B = (const float*)d_in[1];
    float* C = (float*)d_out;

    unsigned short* Ab = (unsigned short*)d_ws;              // 32 MiB
    unsigned short* Bt = Ab + (size_t)N * N;                 // 32 MiB

    prep_kernel<<<dim3(N / 64, N / 64), dim3(256), 0, stream>>>(A, B, Ab, Bt, C);
    trimm_kernel<<<dim3(NWG), dim3(256), 0, stream>>>(Ab, Bt, C);
}

// Round 8
// 234.124 us; speedup vs baseline: 27.9423x; 27.9423x over previous
//
#include <hip/hip_runtime.h>

// C = triu(A @ B), A,B upper-triangular fp32 4096x4096.
// R8: depth-2 register prefetch with COMPILE-TIME slot indices (R7's runtime-
// indexed arrays were demoted to scratch: 703MB WRITE_SIZE, 6ms). Phase loop
// unrolled 2x: even phase -> slot/buf 0, odd -> slot/buf 1 (np always even).
// Balanced split-K grid (CH=8, 1000 wgs), K=64 phases, RS=72 padded LDS.

#define N   4096
#define NB  32      // N / BM
#define BM  128
#define PK  64      // K per pipeline phase
#define CH  8       // K-blocks (128 wide) per chunk
#define NWG 1000    // sum over d of (NB-d)*ceil((d+1)/CH)  [NB=32, CH=8]
#define RS  72      // LDS row stride in ushorts (64 + 8 pad)

typedef __attribute__((ext_vector_type(8))) __bf16 bf16x8;
typedef __attribute__((ext_vector_type(4))) float  floatx4;
typedef __attribute__((ext_vector_type(8))) unsigned short ushort8;

__device__ __forceinline__ unsigned short f32_to_bf16_rne(float f) {
    unsigned u = __builtin_bit_cast(unsigned, f);
    unsigned r = u + 0x7fffu + ((u >> 16) & 1u);
    return (unsigned short)(r >> 16);
}

// --- fused prep: A->bf16 (upper blocks), B->bf16 transposed (needed blocks),
//     zero C where trimm won't plain-store (strictly-lower + atomic tiles) ---
__global__ __launch_bounds__(256)
void prep_kernel(const float* __restrict__ A, const float* __restrict__ B,
                 unsigned short* __restrict__ Ab, unsigned short* __restrict__ Bt,
                 float* __restrict__ C) {
    __shared__ float tile[64][65];
    const int bx = blockIdx.x, by = blockIdx.y;      // 64-granule col/row
    const int x0 = bx * 64, y0 = by * 64;
    const int xb = bx >> 1, yb = by >> 1;            // 128-blocks
    const int t  = threadIdx.x;
    const int tr = t >> 2, tc = (t & 3) * 16;        // 64x(16/thread)

    if (xb >= yb) {   // A: needed iff k-block >= row-block
        const float* src = A + (size_t)(y0 + tr) * N + x0 + tc;
        const float4 v0 = ((const float4*)src)[0];
        const float4 v1 = ((const float4*)src)[1];
        const float4 v2 = ((const float4*)src)[2];
        const float4 v3 = ((const float4*)src)[3];
        ushort8 o0, o1;
        o0[0]=f32_to_bf16_rne(v0.x); o0[1]=f32_to_bf16_rne(v0.y);
        o0[2]=f32_to_bf16_rne(v0.z); o0[3]=f32_to_bf16_rne(v0.w);
        o0[4]=f32_to_bf16_rne(v1.x); o0[5]=f32_to_bf16_rne(v1.y);
        o0[6]=f32_to_bf16_rne(v1.z); o0[7]=f32_to_bf16_rne(v1.w);
        o1[0]=f32_to_bf16_rne(v2.x); o1[1]=f32_to_bf16_rne(v2.y);
        o1[2]=f32_to_bf16_rne(v2.z); o1[3]=f32_to_bf16_rne(v2.w);
        o1[4]=f32_to_bf16_rne(v3.x); o1[5]=f32_to_bf16_rne(v3.y);
        o1[6]=f32_to_bf16_rne(v3.z); o1[7]=f32_to_bf16_rne(v3.w);
        unsigned short* dst = Ab + (size_t)(y0 + tr) * N + x0 + tc;
        ((ushort8*)dst)[0] = o0;
        ((ushort8*)dst)[1] = o1;
    }
    if (xb <= yb) {   // Bt[j][k]=B[k][j]: needed iff k-block <= j-block
        const float* src = B + (size_t)(x0 + tr) * N + y0 + tc;   // B[k][j]
        const float4 v0 = ((const float4*)src)[0];
        const float4 v1 = ((const float4*)src)[1];
        const float4 v2 = ((const float4*)src)[2];
        const float4 v3 = ((const float4*)src)[3];
        float* d = &tile[tr][tc];
        d[0]=v0.x; d[1]=v0.y; d[2]=v0.z; d[3]=v0.w;
        d[4]=v1.x; d[5]=v1.y; d[6]=v1.z; d[7]=v1.w;
        d[8]=v2.x; d[9]=v2.y; d[10]=v2.z; d[11]=v2.w;
        d[12]=v3.x; d[13]=v3.y; d[14]=v3.z; d[15]=v3.w;
        __syncthreads();
        ushort8 o0, o1;
        #pragma unroll
        for (int i = 0; i < 8; ++i) o0[i] = f32_to_bf16_rne(tile[tc + i][tr]);
        #pragma unroll
        for (int i = 0; i < 8; ++i) o1[i] = f32_to_bf16_rne(tile[tc + 8 + i][tr]);
        unsigned short* dst = Bt + (size_t)(y0 + tr) * N + x0 + tc;
        ((ushort8*)dst)[0] = o0;
        ((ushort8*)dst)[1] = o1;
    }
    // C zeros: strictly-lower 128-blocks, and atomic tiles (d>=CH)
    if (xb < yb || (xb - yb) >= CH) {
        float4 z = {0.f, 0.f, 0.f, 0.f};
        float* dst = C + (size_t)(y0 + tr) * N + x0 + tc;
        ((float4*)dst)[0] = z; ((float4*)dst)[1] = z;
        ((float4*)dst)[2] = z; ((float4*)dst)[3] = z;
    }
}

// --- split-K triangular MFMA GEMM, K=64 phases, depth-2 reg prefetch,
//     phase loop unrolled 2x for static slot indices ---
__global__ __launch_bounds__(256, 2)
void trimm_kernel(const unsigned short* __restrict__ Ab,
                  const unsigned short* __restrict__ Bt,
                  float* __restrict__ C) {
    __shared__ unsigned short sA[2][BM * RS];   // padded rows (144 B stride)
    __shared__ unsigned short sB[2][BM * RS];

    // ---- decode blockIdx -> (tile bi,bj ; K-chunk); expensive diagonals first
    int rem = blockIdx.x;
    int d = 0, per = 1;
    for (int dd = NB - 1; dd >= 0; --dd) {
        const int p   = (dd + CH) / CH;          // ceil((dd+1)/CH)
        const int cnt = (NB - dd) * p;
        if (rem < cnt) { d = dd; per = p; break; }
        rem -= cnt;
    }
    const int tile  = rem / per;
    const int chunk = rem - tile * per;
    const int bi = tile, bj = tile + d;
    const int c    = d + 1;
    const int base = c / per, extra = c - base * per;
    const int kb0  = bi + chunk * base + (chunk < extra ? chunk : extra);
    const int len  = base + (chunk < extra ? 1 : 0);

    const int tid  = threadIdx.x;
    const int w    = tid >> 6;
    const int lane = tid & 63;
    const int quad = lane >> 4;
    const int l15  = lane & 15;

    const int m0 = (w >> 1) * 64;
    const int n0 = (w & 1) * 64;
    const int row0 = bi * BM;
    const int col0 = bj * BM;

    floatx4 acc[4][4] = {};

    // staging map: wave w stages rows [32w,32w+32); instr i -> row 32w+8i+(lane>>3)
    const int srow8 = lane >> 3;
    const int sk    = (lane & 7) * 8;
    int lofs[4];
    const unsigned short* gA[4];
    const unsigned short* gB[4];
    #pragma unroll
    for (int i = 0; i < 4; ++i) {
        const int r = w * 32 + i * 8 + srow8;
        lofs[i] = r * RS + sk;
        gA[i] = Ab + (size_t)(row0 + r) * N + kb0 * BM + sk;
        gB[i] = Bt + (size_t)(col0 + r) * N + kb0 * BM + sk;
    }

    const int np = len * 2;            // K=64 phases; ALWAYS EVEN, >= 2

    // depth-2 register pipeline, STATIC slots: a0/b0 = even phase, a1/b1 = odd
    ushort8 a0[4], b0[4], a1[4], b1[4];
    #pragma unroll
    for (int i = 0; i < 4; ++i) { a0[i] = *(const ushort8*)gA[i]; gA[i] += PK; }
    #pragma unroll
    for (int i = 0; i < 4; ++i) { b0[i] = *(const ushort8*)gB[i]; gB[i] += PK; }
    #pragma unroll
    for (int i = 0; i < 4; ++i) { a1[i] = *(const ushort8*)gA[i]; gA[i] += PK; }
    #pragma unroll
    for (int i = 0; i < 4; ++i) { b1[i] = *(const ushort8*)gB[i]; gB[i] += PK; }

    for (int ph = 0; ph < np; ph += 2) {
        // ---- even phase: slot 0, LDS buf 0
        #pragma unroll
        for (int i = 0; i < 4; ++i) *(ushort8*)&sA[0][lofs[i]] = a0[i];
        #pragma unroll
        for (int i = 0; i < 4; ++i) *(ushort8*)&sB[0][lofs[i]] = b0[i];
        __syncthreads();
        if (ph + 2 < np) {
            #pragma unroll
            for (int i = 0; i < 4; ++i) { a0[i] = *(const ushort8*)gA[i]; gA[i] += PK; }
            #pragma unroll
            for (int i = 0; i < 4; ++i) { b0[i] = *(const ushort8*)gB[i]; gB[i] += PK; }
        }
        #pragma unroll
        for (int h = 0; h < 2; ++h) {
            bf16x8 af[4], bfr[4];
            #pragma unroll
            for (int t = 0; t < 4; ++t) {
                af[t]  = *(const bf16x8*)&sA[0][(m0 + t * 16 + l15) * RS + h * 32 + quad * 8];
                bfr[t] = *(const bf16x8*)&sB[0][(n0 + t * 16 + l15) * RS + h * 32 + quad * 8];
            }
            #pragma unroll
            for (int tm = 0; tm < 4; ++tm)
                #pragma unroll
                for (int tn = 0; tn < 4; ++tn)
                    acc[tm][tn] = __builtin_amdgcn_mfma_f32_16x16x32_bf16(
                        af[tm], bfr[tn], acc[tm][tn], 0, 0, 0);
        }

        // ---- odd phase: slot 1, LDS buf 1
        #pragma unroll
        for (int i = 0; i < 4; ++i) *(ushort8*)&sA[1][lofs[i]] = a1[i];
        #pragma unroll
        for (int i = 0; i < 4; ++i) *(ushort8*)&sB[1][lofs[i]] = b1[i];
        __syncthreads();
        if (ph + 3 < np) {
            #pragma unroll
            for (int i = 0; i < 4; ++i) { a1[i] = *(const ushort8*)gA[i]; gA[i] += PK; }
            #pragma unroll
            for (int i = 0; i < 4; ++i) { b1[i] = *(const ushort8*)gB[i]; gB[i] += PK; }
        }
        #pragma unroll
        for (int h = 0; h < 2; ++h) {
            bf16x8 af[4], bfr[4];
            #pragma unroll
            for (int t = 0; t < 4; ++t) {
                af[t]  = *(const bf16x8*)&sA[1][(m0 + t * 16 + l15) * RS + h * 32 + quad * 8];
                bfr[t] = *(const bf16x8*)&sB[1][(n0 + t * 16 + l15) * RS + h * 32 + quad * 8];
            }
            #pragma unroll
            for (int tm = 0; tm < 4; ++tm)
                #pragma unroll
                for (int tn = 0; tn < 4; ++tn)
                    acc[tm][tn] = __builtin_amdgcn_mfma_f32_16x16x32_bf16(
                        af[tm], bfr[tn], acc[tm][tn], 0, 0, 0);
        }
    }

    // ---- epilogue. C/D layout: col=lane&15, row=quad*4+r.
    #pragma unroll
    for (int tm = 0; tm < 4; ++tm) {
        const int grow_base = row0 + m0 + tm * 16 + quad * 4;
        #pragma unroll
        for (int tn = 0; tn < 4; ++tn) {
            const int gcol = col0 + n0 + tn * 16 + l15;
            #pragma unroll
            for (int r = 0; r < 4; ++r) {
                const int grow = grow_base + r;
                float* p = C + (size_t)grow * N + gcol;
                const float v = acc[tm][tn][r];
                if (per > 1) {
                    atomicAdd(p, v);           // tile pre-zeroed by prep
                } else if (d != 0) {
                    *p = v;                    // sole writer, full block
                } else {
                    *p = (gcol >= grow) ? v : 0.0f;   // diagonal block
                }
            }
        }
    }
}

extern "C" void kernel_launch(void* const* d_in, const int* in_sizes, int n_in,
                              void* d_out, int out_size, void* d_ws, size_t ws_size,
                              hipStream_t stream) {
    const float* A = (const float*)d_in[0];
    const float* B = (const float*)d_in[1];
    float* C = (float*)d_out;

    unsigned short* Ab = (unsigned short*)d_ws;              // 32 MiB
    unsigned short* Bt = Ab + (size_t)N * N;                 // 32 MiB

    prep_kernel<<<dim3(N / 64, N / 64), dim3(256), 0, stream>>>(A, B, Ab, Bt, C);
    trimm_kernel<<<dim3(NWG), dim3(256), 0, stream>>>(Ab, Bt, C);
}